// Round 15
// baseline (1797.812 us; speedup 1.0000x reference)
//
#include <hip/hip_runtime.h>

// ---------------------------------------------------------------------------
// MusicLSTM: B=256, T=2048, I=2, H=128 (4H=512 gates), P=129 pitches.
//   prep_k   : note_W+dur_W -> f16 Wn[144][128] in ws
//   lstm10_k : HETEROGENEOUS PIPE PAIRING. 128 WGs x 512 thr (8 waves,
//              2/SIMD) per WG; WG g owns batches A=2g (waves 0-3, r10's
//              proven MFMA body: matrix pipe) and B=2g+1 (waves 4-7, r12's
//              proven dot2 body: VALU pipe). With round-robin wave->SIMD
//              mapping, each SIMD hosts one MFMA-wave + one dot2-wave of
//              INDEPENDENT recurrences (m114: concurrent, max not sum) --
//              each fills the other's serial stalls (ds h round-trip ~170,
//              trans chain ~140) that bounded every single-batch structure
//              at ~1190 cyc/step. Shared barrier; both bodies loop to
//              max(lenA,lenB) with per-batch masking (identical barrier
//              counts; wave-uniform branch). hs stores stay in flight
//              (lgkm-only per-step drain); x in 128-step LDS chunks.
//   proj_k   : MFMA f16 GEMM over hs -> note/dur logits, masked rows zeroed.
// Fragment layouts as verified by proj_k/r10. Static reg indexing only
// (rule #20).
// ---------------------------------------------------------------------------

typedef _Float16 f16;
typedef _Float16 f16x2 __attribute__((ext_vector_type(2)));
typedef _Float16 f16x8 __attribute__((ext_vector_type(8)));
typedef float    f32x4 __attribute__((ext_vector_type(4)));

#define B_  256
#define T_  2048
#define H_  128
#define P_  129

static constexpr size_t NOTE_N   = (size_t)B_ * T_ * P_;
static constexpr size_t DUR_BASE = NOTE_N;
static constexpr size_t HT_BASE  = DUR_BASE + (size_t)B_ * T_;
static constexpr size_t CT_BASE  = HT_BASE + (size_t)B_ * H_;

#if defined(__has_builtin)
#if __has_builtin(__builtin_amdgcn_fdot2)
#define HAVE_FDOT2 1
#endif
#if __has_builtin(__builtin_amdgcn_exp2f)
#define EXP2F(x) __builtin_amdgcn_exp2f(x)
#endif
#endif
#ifndef EXP2F
#define EXP2F(x) __expf((x) * 0.6931471805599453f)
#endif

__device__ __forceinline__ float dot2_acc(f16x2 a, f16x2 b, float c) {
#ifdef HAVE_FDOT2
    return __builtin_amdgcn_fdot2(a, b, c, false);
#else
    return c + (float)a[0] * (float)b[0] + (float)a[1] * (float)b[1];
#endif
}

__device__ __forceinline__ float fast_rcp(float x) { return __builtin_amdgcn_rcpf(x); }

__device__ __forceinline__ float sigmoid_f(float x) {
    float e = EXP2F(-1.44269504f * x);
    return fast_rcp(1.f + e);
}
__device__ __forceinline__ float tanh_f(float x) {
    float e = EXP2F(2.885390082f * x);
    return (e - 1.f) * fast_rcp(e + 1.f);
}

// pair all-reduce (adjacent lanes 2j/2j+1) via DPP quad_perm [1,0,3,2]
__device__ __forceinline__ float pair_allsum(float v) {
    int a = __float_as_int(v);
    v += __int_as_float(__builtin_amdgcn_mov_dpp(a, 0xB1, 0xF, 0xF, true));
    return v;
}

// hs row bt lives at the front of note row bt, rounded up to 16B alignment.
__device__ __forceinline__ f16* hs_row(float* out, int bt) {
    size_t byteoff = ((size_t)bt * (P_ * 4) + 15) & ~(size_t)15;
    return (f16*)((char*)out + byteoff);
}

#define STEP_BARRIER()                                         \
    asm volatile("s_waitcnt lgkmcnt(0)" ::: "memory");         \
    __builtin_amdgcn_sched_barrier(0);                         \
    __builtin_amdgcn_s_barrier();                              \
    __builtin_amdgcn_sched_barrier(0);

// ---------------------------------------------------------------------------
__global__ __launch_bounds__(256) void prep_k(const float* __restrict__ note_W,
                                              const float* __restrict__ dur_W,
                                              f16* __restrict__ Wn) {
    int i = threadIdx.x + blockIdx.x * 256;
    if (i >= 144 * 128) return;
    int row = i >> 7, k = i & 127;
    float v = 0.f;
    if (row < 129)       v = note_W[row * 128 + k];
    else if (row == 129) v = dur_W[k];
    Wn[i] = (f16)v;
}

// ---------------------------------------------------------------------------
__global__ __launch_bounds__(512, 2) void lstm10_k(const float* __restrict__ x,
                                                   const int* __restrict__ lengths,
                                                   const float* __restrict__ W_ih,
                                                   const float* __restrict__ W_hh,
                                                   float* __restrict__ out) {
    __shared__ __align__(16) f16 h_shA[2][H_];   // batch A h double-buffer
    __shared__ __align__(16) f16 h_shB[2][H_];   // batch B h double-buffer
    __shared__ __align__(8) float2 xsA[128];
    __shared__ __align__(8) float2 xsB[128];

    const int tid = threadIdx.x;
    const int g = blockIdx.x;
    const int bA = 2 * g, bB = 2 * g + 1;
    const int lenA = lengths[bA], lenB = lengths[bB];
    const int maxlen = max(lenA, lenB);

    if (tid < 256) ((f16*)h_shA)[tid] = (f16)0.f;
    else           ((f16*)h_shB)[tid - 256] = (f16)0.f;

    if (tid < 256) {
        // =================== waves 0-3: MFMA body, batch A ==================
        const int w = tid >> 6, l = tid & 63;
        const int p = l & 15, q = l >> 4;
        const int sel = q >> 1;
        const int j = 16 * w + 64 * sel + p;
        const bool writer = ((q & 1) == 0);

        f16x8 Bf[8][4];
        float wxx[8], wxy[8];
#pragma unroll
        for (int s = 0; s < 8; s++) {
            const int c = 16 * (w + 4 * s) + p;
            const float* wr = W_hh + (size_t)c * H_ + 8 * q;
#pragma unroll
            for (int kt = 0; kt < 4; kt++) {
                float4 v1 = *(const float4*)(wr + 32 * kt);
                float4 v2 = *(const float4*)(wr + 32 * kt + 4);
                f16x8 f;
                f[0]=(f16)v1.x; f[1]=(f16)v1.y; f[2]=(f16)v1.z; f[3]=(f16)v1.w;
                f[4]=(f16)v2.x; f[5]=(f16)v2.y; f[6]=(f16)v2.z; f[7]=(f16)v2.w;
                Bf[s][kt] = f;
            }
            wxx[s] = W_ih[2 * c];
            wxy[s] = W_ih[2 * c + 1];
        }

        char* hp = (char*)out + (size_t)bA * (T_ * 516ULL) + 2 * j;
        const f32x4 z4 = {0.f, 0.f, 0.f, 0.f};
        float c_reg = 0.f, h_reg = 0.f;

        for (int t = 0; t < maxlen; t++) {
            if ((t & 127) == 0) {
                __syncthreads();
                if (tid < 128)
                    xsA[tid] = *(const float2*)(x + (size_t)bA * T_ * 2 + (size_t)(t + tid) * 2);
                __syncthreads();
            }
            const int cur = t & 1;

            f16x8 Af[4];
#pragma unroll
            for (int kt = 0; kt < 4; kt++)
                Af[kt] = *(const f16x8*)(&h_shA[cur][32 * kt + 8 * q]);

            f32x4 acc[8];
#pragma unroll
            for (int s = 0; s < 8; s++)
                acc[s] = __builtin_amdgcn_mfma_f32_16x16x32_f16(Af[0], Bf[s][0], z4, 0, 0, 0);
#pragma unroll
            for (int kt = 1; kt < 4; kt++) {
#pragma unroll
                for (int s = 0; s < 8; s++)
                    acc[s] = __builtin_amdgcn_mfma_f32_16x16x32_f16(
                        Af[kt], Bf[s][kt], acc[s], 0, 0, 0);
            }

            const float2 xv = xsA[t & 127];
            float G[4];
#pragma unroll
            for (int tt = 0; tt < 4; tt++) {
                float ga = acc[2 * tt][0] +
                           __builtin_fmaf(wxy[2 * tt], xv.y, wxx[2 * tt] * xv.x);
                float gb = acc[2 * tt + 1][0] +
                           __builtin_fmaf(wxy[2 * tt + 1], xv.y, wxx[2 * tt + 1] * xv.x);
                G[tt] = sel ? gb : ga;
            }

            const float ig = sigmoid_f(G[0]);
            const float fg = sigmoid_f(G[1]);
            const float gg = tanh_f(G[2]);
            const float og = sigmoid_f(G[3]);
            float cn = __builtin_fmaf(fg, c_reg, ig * gg);
            float hn = og * tanh_f(fminf(fmaxf(cn, -15.f), 15.f));
            const bool m = (t < lenA);
            c_reg = m ? cn : c_reg;
            h_reg = m ? hn : h_reg;

            if (writer) {
                const f16 h16 = (f16)h_reg;
                if (m) *(f16*)hp = h16;       // global, stays in flight
                h_shA[cur ^ 1][j] = h16;      // LDS (lgkm)
            }
            hp += 512 + (((t & 3) == 0) ? 16 : 0);

            STEP_BARRIER();
        }

        if (writer) {
            out[HT_BASE + (size_t)bA * H_ + j] = h_reg;
            out[CT_BASE + (size_t)bA * H_ + j] = c_reg;
        }
    } else {
        // =================== waves 4-7: dot2 body, batch B ==================
        const int ltid = tid - 256;
        const int j = ltid >> 1;      // column 0..127
        const int kh = ltid & 1;      // K-half
        const bool writer = (kh == 0);

        union WU { f16x8 v8[32]; f16x2 v2[128]; } wu;
        float wix[4], wiy[4];
#pragma unroll
        for (int gg_ = 0; gg_ < 4; gg_++) {
            const int c = j + 128 * gg_;
            const float* wr = W_hh + (size_t)c * H_ + 64 * kh;
#pragma unroll
            for (int i = 0; i < 8; i++) {
                float4 v1 = *(const float4*)(wr + 8 * i);
                float4 v2 = *(const float4*)(wr + 8 * i + 4);
                f16x8 f;
                f[0]=(f16)v1.x; f[1]=(f16)v1.y; f[2]=(f16)v1.z; f[3]=(f16)v1.w;
                f[4]=(f16)v2.x; f[5]=(f16)v2.y; f[6]=(f16)v2.z; f[7]=(f16)v2.w;
                wu.v8[8 * gg_ + i] = f;
            }
            wix[gg_] = W_ih[2 * c];
            wiy[gg_] = W_ih[2 * c + 1];
        }

        char* hp = (char*)out + (size_t)bB * (T_ * 516ULL) + 2 * j;
        float c_reg = 0.f, h_reg = 0.f;

        for (int t = 0; t < maxlen; t++) {
            if ((t & 127) == 0) {
                __syncthreads();
                if (ltid < 128)
                    xsB[ltid] = *(const float2*)(x + (size_t)bB * T_ * 2 + (size_t)(t + ltid) * 2);
                __syncthreads();
            }
            const int cur = t & 1;

            union HU { f16x8 v8[8]; f16x2 v2[32]; } hu;
#pragma unroll
            for (int i = 0; i < 8; i++)
                hu.v8[i] = *(const f16x8*)(&h_shB[cur][64 * kh + 8 * i]);

            float a0 = 0.f, a1 = 0.f, a2 = 0.f, a3 = 0.f;
            float b0 = 0.f, b1 = 0.f, b2 = 0.f, b3 = 0.f;
#pragma unroll
            for (int i = 0; i < 16; i++) {
                f16x2 hp0 = hu.v2[i];
                f16x2 hq0 = hu.v2[i + 16];
                a0 = dot2_acc(wu.v2[i],       hp0, a0);
                b0 = dot2_acc(wu.v2[i + 16],  hq0, b0);
                a1 = dot2_acc(wu.v2[i + 32],  hp0, a1);
                b1 = dot2_acc(wu.v2[i + 48],  hq0, b1);
                a2 = dot2_acc(wu.v2[i + 64],  hp0, a2);
                b2 = dot2_acc(wu.v2[i + 80],  hq0, b2);
                a3 = dot2_acc(wu.v2[i + 96],  hp0, a3);
                b3 = dot2_acc(wu.v2[i + 112], hq0, b3);
            }
            a0 += b0; a1 += b1; a2 += b2; a3 += b3;
            a0 = pair_allsum(a0);
            a1 = pair_allsum(a1);
            a2 = pair_allsum(a2);
            a3 = pair_allsum(a3);
            const float2 xv = xsB[t & 127];
            a0 += __builtin_fmaf(wiy[0], xv.y, wix[0] * xv.x);
            a1 += __builtin_fmaf(wiy[1], xv.y, wix[1] * xv.x);
            a2 += __builtin_fmaf(wiy[2], xv.y, wix[2] * xv.x);
            a3 += __builtin_fmaf(wiy[3], xv.y, wix[3] * xv.x);

            const float ig = sigmoid_f(a0);
            const float fg = sigmoid_f(a1);
            const float gg = tanh_f(a2);
            const float og = sigmoid_f(a3);
            float cn = __builtin_fmaf(fg, c_reg, ig * gg);
            float hn = og * tanh_f(fminf(fmaxf(cn, -15.f), 15.f));
            const bool m = (t < lenB);
            c_reg = m ? cn : c_reg;
            h_reg = m ? hn : h_reg;

            if (writer) {
                const f16 h16 = (f16)h_reg;
                if (m) *(f16*)hp = h16;       // global, stays in flight
                h_shB[cur ^ 1][j] = h16;      // LDS (lgkm)
            }
            hp += 512 + (((t & 3) == 0) ? 16 : 0);

            STEP_BARRIER();
        }

        if (writer) {
            out[HT_BASE + (size_t)bB * H_ + j] = h_reg;
            out[CT_BASE + (size_t)bB * H_ + j] = c_reg;
        }
    }
}

// ---------------------------------------------------------------------------
// Projection GEMM: C[bt, n] = hs[bt,:] . Wn[n,:] + bias, masked by t<len.
__global__ __launch_bounds__(256) void proj_k(const int* __restrict__ lengths,
                                              const f16* __restrict__ Wn,
                                              const float* __restrict__ note_b,
                                              const float* __restrict__ dur_b,
                                              float* __restrict__ out) {
    __shared__ __align__(16) f16 wn_sh[144 * 136];

    const int tid = threadIdx.x;
    {
        unsigned int* dst = (unsigned int*)wn_sh;
        const unsigned int* src = (const unsigned int*)Wn;
        for (int w = tid; w < 144 * 64; w += 256) {
            int row = w >> 6, cw = w & 63;
            dst[row * 68 + cw] = src[w];
        }
    }
    __syncthreads();

    const int wv = tid >> 6;
    const int l = tid & 63;
    const int tile = blockIdx.x * 4 + wv;
    const int bt0 = tile * 16;
    const int b = bt0 >> 11;
    const int t0 = bt0 & 2047;
    const int len = lengths[b];
    const int r16 = l & 15, q = l >> 4;

    f32x4 acc[9];
#pragma unroll
    for (int nf = 0; nf < 9; nf++) acc[nf] = f32x4{0.f, 0.f, 0.f, 0.f};

    const bool live = (t0 < len);
    if (live) {
        f16x8 a[4];
        {
            const f16* ar = hs_row(out, bt0 + r16);
#pragma unroll
            for (int kk = 0; kk < 4; kk++)
                a[kk] = *(const f16x8*)(ar + kk * 32 + q * 8);
        }
#pragma unroll
        for (int nf = 0; nf < 9; nf++) {
            const f16* brow = wn_sh + (nf * 16 + r16) * 136 + q * 8;
#pragma unroll
            for (int kk = 0; kk < 4; kk++) {
                f16x8 bb = *(const f16x8*)(brow + kk * 32);
                acc[nf] = __builtin_amdgcn_mfma_f32_16x16x32_f16(a[kk], bb, acc[nf], 0, 0, 0);
            }
        }
    }

#pragma unroll
    for (int nf = 0; nf < 9; nf++) {
        int col = nf * 16 + r16;
        float bias = 0.f;
        if (col < 129)       bias = note_b[col];
        else if (col == 129) bias = dur_b[0];
#pragma unroll
        for (int r = 0; r < 4; r++) {
            int rowbt = bt0 + q * 4 + r;
            int t = t0 + q * 4 + r;
            float v = (t < len) ? (acc[nf][r] + bias) : 0.f;
            if (col < 129)
                out[(size_t)rowbt * P_ + col] = v;
            else if (col == 129)
                out[DUR_BASE + rowbt] = v;
        }
    }
}

// ---------------------------------------------------------------------------
extern "C" void kernel_launch(void* const* d_in, const int* in_sizes, int n_in,
                              void* d_out, int out_size, void* d_ws, size_t ws_size,
                              hipStream_t stream) {
    const float* x       = (const float*)d_in[0];
    const int*   lengths = (const int*)d_in[1];
    const float* W_ih    = (const float*)d_in[2];
    const float* W_hh    = (const float*)d_in[3];
    const float* note_W  = (const float*)d_in[4];
    const float* note_b  = (const float*)d_in[5];
    const float* dur_W   = (const float*)d_in[6];
    const float* dur_b   = (const float*)d_in[7];
    float* out = (float*)d_out;
    f16* Wn = (f16*)d_ws;

    prep_k<<<72, 256, 0, stream>>>(note_W, dur_W, Wn);
    lstm10_k<<<B_ / 2, 512, 0, stream>>>(x, lengths, W_ih, W_hh, out);
    proj_k<<<(B_ * T_) / 64, 256, 0, stream>>>(lengths, Wn, note_b, dur_b, out);
}

// Round 16
// 991.537 us; speedup vs baseline: 1.8132x; 1.8132x over previous
//
#include <hip/hip_runtime.h>

// ---------------------------------------------------------------------------
// MusicLSTM: B=256, T=2048, I=2, H=128 (4H=512 gates), P=129 pitches.
//   prep_k   : note_W+dur_W -> f16 Wn[144][128] in ws
//   lstm11_k : r10's measured-best structure (1 WG = 256 thr = 4 waves =
//              1/SIMD per batch; gates[512] = W_hh . h via MFMA 16x16x32
//              with h broadcast as A; wave w owns n-tiles {w+4s}; lane (p,q)
//              extracts its column's gates with STATIC acc indices + cndmask
//              -- rule #20) with serial-tail trims:
//                (1) W_ih coeffs pre-selected by sel at init (one cndmask at
//                    setup instead of 2x FMA-sets + select per step),
//                (2) MFMA chains split 2x2-deep (acc/acc2; last MFMA depends
//                    on a 2-chain, not 4-chain -> shorter drain before
//                    extraction),
//              One raw s_barrier per step (lgkm-only drain; per-step global
//              hs stores stay in flight; NO global loads inside the step --
//              r13's vmcnt hazard). h double-buffered in LDS; x staged in
//              128-step LDS chunks; incremental hs store addressing.
//   proj_k   : MFMA f16 GEMM over hs -> note/dur logits, masked rows zeroed.
// Fragment layout conventions (verified by the passing proj_k / r10):
//   A: lane l holds A[m=l&15][k=32*kt+8*(l>>4)+e], e=0..7
//   B: lane l holds B[n=l&15][k=32*kt+8*(l>>4)+e]
//   D: lane l reg r holds D[m=(l>>4)*4+r][n=l&15]
// ---------------------------------------------------------------------------

typedef _Float16 f16;
typedef _Float16 f16x8 __attribute__((ext_vector_type(8)));
typedef float    f32x4 __attribute__((ext_vector_type(4)));

#define B_  256
#define T_  2048
#define H_  128
#define P_  129

static constexpr size_t NOTE_N   = (size_t)B_ * T_ * P_;
static constexpr size_t DUR_BASE = NOTE_N;
static constexpr size_t HT_BASE  = DUR_BASE + (size_t)B_ * T_;
static constexpr size_t CT_BASE  = HT_BASE + (size_t)B_ * H_;

#if defined(__has_builtin)
#if __has_builtin(__builtin_amdgcn_exp2f)
#define EXP2F(x) __builtin_amdgcn_exp2f(x)
#endif
#endif
#ifndef EXP2F
#define EXP2F(x) __expf((x) * 0.6931471805599453f)
#endif

__device__ __forceinline__ float fast_rcp(float x) { return __builtin_amdgcn_rcpf(x); }

__device__ __forceinline__ float sigmoid_f(float x) {
    float e = EXP2F(-1.44269504f * x);
    return fast_rcp(1.f + e);
}
__device__ __forceinline__ float tanh_f(float x) {
    float e = EXP2F(2.885390082f * x);
    return (e - 1.f) * fast_rcp(e + 1.f);
}

// hs row bt lives at the front of note row bt, rounded up to 16B alignment.
__device__ __forceinline__ f16* hs_row(float* out, int bt) {
    size_t byteoff = ((size_t)bt * (P_ * 4) + 15) & ~(size_t)15;
    return (f16*)((char*)out + byteoff);
}

// ---------------------------------------------------------------------------
__global__ __launch_bounds__(256) void prep_k(const float* __restrict__ note_W,
                                              const float* __restrict__ dur_W,
                                              f16* __restrict__ Wn) {
    int i = threadIdx.x + blockIdx.x * 256;
    if (i >= 144 * 128) return;
    int row = i >> 7, k = i & 127;
    float v = 0.f;
    if (row < 129)       v = note_W[row * 128 + k];
    else if (row == 129) v = dur_W[k];
    Wn[i] = (f16)v;
}

// ---------------------------------------------------------------------------
__global__ __launch_bounds__(256, 1) void lstm11_k(const float* __restrict__ x,
                                                   const int* __restrict__ lengths,
                                                   const float* __restrict__ W_ih,
                                                   const float* __restrict__ W_hh,
                                                   float* __restrict__ out) {
    __shared__ __align__(16) f16 h_sh[2][H_];   // double-buffered h (512 B)
    __shared__ __align__(8) float2 xs[128];     // x chunk: 128 steps (1 KB)

    const int tid = threadIdx.x;
    const int b = blockIdx.x;
    const int w = tid >> 6;       // wave 0..3 (one per SIMD)
    const int l = tid & 63;
    const int p = l & 15;
    const int q = l >> 4;
    const int sel = q >> 1;                    // 0: col j=16w+p, 1: j=16w+64+p
    const int j = 16 * w + 64 * sel + p;       // this lane's hidden column
    const bool writer = ((q & 1) == 0);

    // B-fragments: 8 gate-row groups nt = w+4s; global row c = 16*nt + p.
    // (s = 2*tt + sel maps to gate tt of this lane's column.)
    f16x8 Bf[8][4];
    float wxx[8], wxy[8];
#pragma unroll
    for (int s = 0; s < 8; s++) {
        const int c = 16 * (w + 4 * s) + p;
        const float* wr = W_hh + (size_t)c * H_ + 8 * q;
#pragma unroll
        for (int kt = 0; kt < 4; kt++) {
            float4 v1 = *(const float4*)(wr + 32 * kt);
            float4 v2 = *(const float4*)(wr + 32 * kt + 4);
            f16x8 f;
            f[0] = (f16)v1.x; f[1] = (f16)v1.y; f[2] = (f16)v1.z; f[3] = (f16)v1.w;
            f[4] = (f16)v2.x; f[5] = (f16)v2.y; f[6] = (f16)v2.z; f[7] = (f16)v2.w;
            Bf[s][kt] = f;
        }
        wxx[s] = W_ih[2 * c];
        wxy[s] = W_ih[2 * c + 1];
    }
    // Pre-select this lane's W_ih coefficients (cndmask once at init):
    const float wx0 = sel ? wxx[1] : wxx[0], wy0 = sel ? wxy[1] : wxy[0];
    const float wx1 = sel ? wxx[3] : wxx[2], wy1 = sel ? wxy[3] : wxy[2];
    const float wx2 = sel ? wxx[5] : wxx[4], wy2 = sel ? wxy[5] : wxy[4];
    const float wx3 = sel ? wxx[7] : wxx[6], wy3 = sel ? wxy[7] : wxy[6];

    const int len = lengths[b];
    if (tid < 2 * H_) ((f16*)h_sh)[tid] = (f16)0.f;

    // incremental hs store pointer (row stride pattern 528,512,512,512)
    char* hp = (char*)out + (size_t)b * (T_ * 516ULL) + 2 * j;

    const f32x4 z4 = {0.f, 0.f, 0.f, 0.f};
    float c_reg = 0.f, h_reg = 0.f;

    for (int t = 0; t < len; t++) {
        if ((t & 127) == 0) {
            // refill x chunk [t, t+128). Full drain barrier, amortized /128.
            __syncthreads();
            if (tid < 128)
                xs[tid] = *(const float2*)(x + (size_t)b * T_ * 2 + (size_t)(t + tid) * 2);
            __syncthreads();
        }
        const int cur = t & 1;

        // A-fragments: h broadcast (same 16B for all lanes of a q-group)
        f16x8 Af[4];
#pragma unroll
        for (int kt = 0; kt < 4; kt++)
            Af[kt] = *(const f16x8*)(&h_sh[cur][32 * kt + 8 * q]);

        // 2x2-deep MFMA chains per tile (shorter drain than 4-deep)
        f32x4 acc[8], acc2[8];
#pragma unroll
        for (int s = 0; s < 8; s++) {
            acc[s]  = __builtin_amdgcn_mfma_f32_16x16x32_f16(Af[0], Bf[s][0], z4, 0, 0, 0);
            acc2[s] = __builtin_amdgcn_mfma_f32_16x16x32_f16(Af[2], Bf[s][2], z4, 0, 0, 0);
        }
#pragma unroll
        for (int s = 0; s < 8; s++) {
            acc[s]  = __builtin_amdgcn_mfma_f32_16x16x32_f16(Af[1], Bf[s][1], acc[s],  0, 0, 0);
            acc2[s] = __builtin_amdgcn_mfma_f32_16x16x32_f16(Af[3], Bf[s][3], acc2[s], 0, 0, 0);
        }

        const float2 xv = xs[t & 127];
        // STATIC acc indices; lane's column selected via cndmask (rule #20)
        float g0a = acc[0][0] + acc2[0][0], g0b = acc[1][0] + acc2[1][0];
        float g1a = acc[2][0] + acc2[2][0], g1b = acc[3][0] + acc2[3][0];
        float g2a = acc[4][0] + acc2[4][0], g2b = acc[5][0] + acc2[5][0];
        float g3a = acc[6][0] + acc2[6][0], g3b = acc[7][0] + acc2[7][0];
        float G0 = (sel ? g0b : g0a) + __builtin_fmaf(wy0, xv.y, wx0 * xv.x);
        float G1 = (sel ? g1b : g1a) + __builtin_fmaf(wy1, xv.y, wx1 * xv.x);
        float G2 = (sel ? g2b : g2a) + __builtin_fmaf(wy2, xv.y, wx2 * xv.x);
        float G3 = (sel ? g3b : g3a) + __builtin_fmaf(wy3, xv.y, wx3 * xv.x);

        const float ig = sigmoid_f(G0);
        const float fg = sigmoid_f(G1);
        const float gg = tanh_f(G2);
        const float og = sigmoid_f(G3);
        c_reg = __builtin_fmaf(fg, c_reg, ig * gg);
        h_reg = og * tanh_f(fminf(fmaxf(c_reg, -15.f), 15.f));

        if (writer) {
            const f16 h16 = (f16)h_reg;
            *(f16*)hp = h16;            // global, stays in flight
            h_sh[cur ^ 1][j] = h16;     // LDS (lgkm)
        }
        hp += 512 + (((t & 3) == 0) ? 16 : 0);

        // drain LDS only; global hs stores remain outstanding
        asm volatile("s_waitcnt lgkmcnt(0)" ::: "memory");
        __builtin_amdgcn_sched_barrier(0);
        __builtin_amdgcn_s_barrier();
        __builtin_amdgcn_sched_barrier(0);
    }

    if (writer) {
        out[HT_BASE + (size_t)b * H_ + j] = h_reg;
        out[CT_BASE + (size_t)b * H_ + j] = c_reg;
    }
}

// ---------------------------------------------------------------------------
// Projection GEMM: C[bt, n] = hs[bt,:] . Wn[n,:] + bias, masked by t<len.
__global__ __launch_bounds__(256) void proj_k(const int* __restrict__ lengths,
                                              const f16* __restrict__ Wn,
                                              const float* __restrict__ note_b,
                                              const float* __restrict__ dur_b,
                                              float* __restrict__ out) {
    __shared__ __align__(16) f16 wn_sh[144 * 136];

    const int tid = threadIdx.x;
    {
        unsigned int* dst = (unsigned int*)wn_sh;
        const unsigned int* src = (const unsigned int*)Wn;
        for (int w = tid; w < 144 * 64; w += 256) {
            int row = w >> 6, cw = w & 63;
            dst[row * 68 + cw] = src[w];
        }
    }
    __syncthreads();

    const int wv = tid >> 6;
    const int l = tid & 63;
    const int tile = blockIdx.x * 4 + wv;
    const int bt0 = tile * 16;
    const int b = bt0 >> 11;
    const int t0 = bt0 & 2047;
    const int len = lengths[b];
    const int r16 = l & 15, q = l >> 4;

    f32x4 acc[9];
#pragma unroll
    for (int nf = 0; nf < 9; nf++) acc[nf] = f32x4{0.f, 0.f, 0.f, 0.f};

    const bool live = (t0 < len);
    if (live) {
        f16x8 a[4];
        {
            const f16* ar = hs_row(out, bt0 + r16);
#pragma unroll
            for (int kk = 0; kk < 4; kk++)
                a[kk] = *(const f16x8*)(ar + kk * 32 + q * 8);
        }
#pragma unroll
        for (int nf = 0; nf < 9; nf++) {
            const f16* brow = wn_sh + (nf * 16 + r16) * 136 + q * 8;
#pragma unroll
            for (int kk = 0; kk < 4; kk++) {
                f16x8 bb = *(const f16x8*)(brow + kk * 32);
                acc[nf] = __builtin_amdgcn_mfma_f32_16x16x32_f16(a[kk], bb, acc[nf], 0, 0, 0);
            }
        }
    }

#pragma unroll
    for (int nf = 0; nf < 9; nf++) {
        int col = nf * 16 + r16;
        float bias = 0.f;
        if (col < 129)       bias = note_b[col];
        else if (col == 129) bias = dur_b[0];
#pragma unroll
        for (int r = 0; r < 4; r++) {
            int rowbt = bt0 + q * 4 + r;
            int t = t0 + q * 4 + r;
            float v = (t < len) ? (acc[nf][r] + bias) : 0.f;
            if (col < 129)
                out[(size_t)rowbt * P_ + col] = v;
            else if (col == 129)
                out[DUR_BASE + rowbt] = v;
        }
    }
}

// ---------------------------------------------------------------------------
extern "C" void kernel_launch(void* const* d_in, const int* in_sizes, int n_in,
                              void* d_out, int out_size, void* d_ws, size_t ws_size,
                              hipStream_t stream) {
    const float* x       = (const float*)d_in[0];
    const int*   lengths = (const int*)d_in[1];
    const float* W_ih    = (const float*)d_in[2];
    const float* W_hh    = (const float*)d_in[3];
    const float* note_W  = (const float*)d_in[4];
    const float* note_b  = (const float*)d_in[5];
    const float* dur_W   = (const float*)d_in[6];
    const float* dur_b   = (const float*)d_in[7];
    float* out = (float*)d_out;
    f16* Wn = (f16*)d_ws;

    prep_k<<<72, 256, 0, stream>>>(note_W, dur_W, Wn);
    lstm11_k<<<B_, 256, 0, stream>>>(x, lengths, W_ih, W_hh, out);
    proj_k<<<(B_ * T_) / 64, 256, 0, stream>>>(lengths, Wn, note_b, dur_b, out);
}

// Round 18
// 979.181 us; speedup vs baseline: 1.8360x; 1.0126x over previous
//
#include <hip/hip_runtime.h>

// ---------------------------------------------------------------------------
// MusicLSTM: B=256, T=2048, I=2, H=128 (4H=512 gates), P=129 pitches.
//   prep_k   : note_W+dur_W -> f16 Wn[144][128] in ws
//   lstm12_k : r16's structure (1 WG = 256 thr = 4 waves = 1/SIMD per batch;
//              gates[512] = W_hh . h via MFMA 16x16x32, h broadcast as A;
//              wave w owns n-tiles {w+4s}; static acc indices + cndmask;
//              2x2-deep MFMA chains; pre-selected W_ih coeffs; raw per-step
//              s_barrier with lgkm-only drain, hs stores in flight) plus
//              static-overhead elimination:
//                (1) 4-step unroll: cur (0,1,0,1) and hp increments
//                    (528,512,512,512) become compile-time constants; loop
//                    control amortized 4x.
//                (2) refill's leading __syncthreads removed (prev step's
//                    lgkm(0)+s_barrier already drained old-chunk reads; the
//                    trailing one still publishes h-zeroing at t=0).
//              Tail (<4 steps) uses the dynamic body.
//   proj_k   : MFMA f16 GEMM over hs -> note/dur logits, masked rows zeroed.
// Fragment layout conventions (verified by the passing proj_k / r10):
//   A: lane l holds A[m=l&15][k=32*kt+8*(l>>4)+e], e=0..7
//   B: lane l holds B[n=l&15][k=32*kt+8*(l>>4)+e]
//   D: lane l reg r holds D[m=(l>>4)*4+r][n=l&15]
// ---------------------------------------------------------------------------

typedef _Float16 f16;
typedef _Float16 f16x8 __attribute__((ext_vector_type(8)));
typedef float    f32x4 __attribute__((ext_vector_type(4)));

#define B_  256
#define T_  2048
#define H_  128
#define P_  129

static constexpr size_t NOTE_N   = (size_t)B_ * T_ * P_;
static constexpr size_t DUR_BASE = NOTE_N;
static constexpr size_t HT_BASE  = DUR_BASE + (size_t)B_ * T_;
static constexpr size_t CT_BASE  = HT_BASE + (size_t)B_ * H_;

#if defined(__has_builtin)
#if __has_builtin(__builtin_amdgcn_exp2f)
#define EXP2F(x) __builtin_amdgcn_exp2f(x)
#endif
#endif
#ifndef EXP2F
#define EXP2F(x) __expf((x) * 0.6931471805599453f)
#endif

__device__ __forceinline__ float fast_rcp(float x) { return __builtin_amdgcn_rcpf(x); }

__device__ __forceinline__ float sigmoid_f(float x) {
    float e = EXP2F(-1.44269504f * x);
    return fast_rcp(1.f + e);
}
__device__ __forceinline__ float tanh_f(float x) {
    float e = EXP2F(2.885390082f * x);
    return (e - 1.f) * fast_rcp(e + 1.f);
}

// hs row bt lives at the front of note row bt, rounded up to 16B alignment.
__device__ __forceinline__ f16* hs_row(float* out, int bt) {
    size_t byteoff = ((size_t)bt * (P_ * 4) + 15) & ~(size_t)15;
    return (f16*)((char*)out + byteoff);
}

// ---------------------------------------------------------------------------
__global__ __launch_bounds__(256) void prep_k(const float* __restrict__ note_W,
                                              const float* __restrict__ dur_W,
                                              f16* __restrict__ Wn) {
    int i = threadIdx.x + blockIdx.x * 256;
    if (i >= 144 * 128) return;
    int row = i >> 7, k = i & 127;
    float v = 0.f;
    if (row < 129)       v = note_W[row * 128 + k];
    else if (row == 129) v = dur_W[k];
    Wn[i] = (f16)v;
}

// ---------------------------------------------------------------------------
__global__ __launch_bounds__(256, 1) void lstm12_k(const float* __restrict__ x,
                                                   const int* __restrict__ lengths,
                                                   const float* __restrict__ W_ih,
                                                   const float* __restrict__ W_hh,
                                                   float* __restrict__ out) {
    __shared__ __align__(16) f16 h_sh[2][H_];   // double-buffered h (512 B)
    __shared__ __align__(8) float2 xs[128];     // x chunk: 128 steps (1 KB)

    const int tid = threadIdx.x;
    const int b = blockIdx.x;
    const int w = tid >> 6;       // wave 0..3 (one per SIMD)
    const int l = tid & 63;
    const int p = l & 15;
    const int q = l >> 4;
    const int sel = q >> 1;                    // 0: col j=16w+p, 1: j=16w+64+p
    const int j = 16 * w + 64 * sel + p;       // this lane's hidden column
    const bool writer = ((q & 1) == 0);

    // B-fragments: 8 gate-row groups nt = w+4s; global row c = 16*nt + p.
    f16x8 Bf[8][4];
    float wxx[8], wxy[8];
#pragma unroll
    for (int s = 0; s < 8; s++) {
        const int c = 16 * (w + 4 * s) + p;
        const float* wr = W_hh + (size_t)c * H_ + 8 * q;
#pragma unroll
        for (int kt = 0; kt < 4; kt++) {
            float4 v1 = *(const float4*)(wr + 32 * kt);
            float4 v2 = *(const float4*)(wr + 32 * kt + 4);
            f16x8 f;
            f[0] = (f16)v1.x; f[1] = (f16)v1.y; f[2] = (f16)v1.z; f[3] = (f16)v1.w;
            f[4] = (f16)v2.x; f[5] = (f16)v2.y; f[6] = (f16)v2.z; f[7] = (f16)v2.w;
            Bf[s][kt] = f;
        }
        wxx[s] = W_ih[2 * c];
        wxy[s] = W_ih[2 * c + 1];
    }
    // Pre-select this lane's W_ih coefficients (cndmask once at init):
    const float wx0 = sel ? wxx[1] : wxx[0], wy0 = sel ? wxy[1] : wxy[0];
    const float wx1 = sel ? wxx[3] : wxx[2], wy1 = sel ? wxy[3] : wxy[2];
    const float wx2 = sel ? wxx[5] : wxx[4], wy2 = sel ? wxy[5] : wxy[4];
    const float wx3 = sel ? wxx[7] : wxx[6], wy3 = sel ? wxy[7] : wxy[6];

    const int len = lengths[b];
    if (tid < 2 * H_) ((f16*)h_sh)[tid] = (f16)0.f;

    // incremental hs store pointer (row stride pattern 528,512,512,512)
    char* hp = (char*)out + (size_t)b * (T_ * 516ULL) + 2 * j;

    const f32x4 z4 = {0.f, 0.f, 0.f, 0.f};
    float c_reg = 0.f, h_reg = 0.f;
    const float2* xg = (const float2*)(x + (size_t)b * T_ * 2);

// One LSTM step with compile-time CUR/NXT buffer ids, x offset, hp increment.
#define LSTM_STEP(CUR, NXT, XOFF, INC)                                         \
    {                                                                          \
        const float2 xv = xc[XOFF];                                            \
        f16x8 Af[4];                                                           \
        _Pragma("unroll")                                                      \
        for (int kt = 0; kt < 4; kt++)                                         \
            Af[kt] = *(const f16x8*)(&h_sh[CUR][32 * kt + 8 * q]);             \
        f32x4 acc[8], acc2[8];                                                 \
        _Pragma("unroll")                                                      \
        for (int s = 0; s < 8; s++) {                                          \
            acc[s]  = __builtin_amdgcn_mfma_f32_16x16x32_f16(Af[0], Bf[s][0], z4, 0, 0, 0);      \
            acc2[s] = __builtin_amdgcn_mfma_f32_16x16x32_f16(Af[2], Bf[s][2], z4, 0, 0, 0);      \
        }                                                                      \
        _Pragma("unroll")                                                      \
        for (int s = 0; s < 8; s++) {                                          \
            acc[s]  = __builtin_amdgcn_mfma_f32_16x16x32_f16(Af[1], Bf[s][1], acc[s],  0, 0, 0); \
            acc2[s] = __builtin_amdgcn_mfma_f32_16x16x32_f16(Af[3], Bf[s][3], acc2[s], 0, 0, 0); \
        }                                                                      \
        float G0 = (sel ? acc[1][0] + acc2[1][0] : acc[0][0] + acc2[0][0])     \
                   + __builtin_fmaf(wy0, xv.y, wx0 * xv.x);                    \
        float G1 = (sel ? acc[3][0] + acc2[3][0] : acc[2][0] + acc2[2][0])     \
                   + __builtin_fmaf(wy1, xv.y, wx1 * xv.x);                    \
        float G2 = (sel ? acc[5][0] + acc2[5][0] : acc[4][0] + acc2[4][0])     \
                   + __builtin_fmaf(wy2, xv.y, wx2 * xv.x);                    \
        float G3 = (sel ? acc[7][0] + acc2[7][0] : acc[6][0] + acc2[6][0])     \
                   + __builtin_fmaf(wy3, xv.y, wx3 * xv.x);                    \
        const float ig = sigmoid_f(G0);                                        \
        const float fg = sigmoid_f(G1);                                        \
        const float gg = tanh_f(G2);                                           \
        const float og = sigmoid_f(G3);                                        \
        c_reg = __builtin_fmaf(fg, c_reg, ig * gg);                            \
        h_reg = og * tanh_f(fminf(fmaxf(c_reg, -15.f), 15.f));                 \
        if (writer) {                                                          \
            const f16 h16 = (f16)h_reg;                                        \
            *(f16*)hp = h16;            /* global, stays in flight */          \
            h_sh[NXT][j] = h16;         /* LDS (lgkm) */                       \
        }                                                                      \
        hp += (INC);                                                           \
        asm volatile("s_waitcnt lgkmcnt(0)" ::: "memory");                     \
        __builtin_amdgcn_sched_barrier(0);                                     \
        __builtin_amdgcn_s_barrier();                                          \
        __builtin_amdgcn_sched_barrier(0);                                     \
    }

    int t = 0;
    for (; t + 4 <= len; t += 4) {
        if ((t & 127) == 0) {
            // refill x chunk [t, t+128). Prev step's lgkm+barrier already
            // drained old-chunk reads; one syncthreads publishes the writes
            // (and, at t=0, the h_sh zeroing).
            if (tid < 128) xs[tid] = xg[t + tid];
            __syncthreads();
        }
        const float2* xc = &xs[t & 127];
        LSTM_STEP(0, 1, 0, 528)
        LSTM_STEP(1, 0, 1, 512)
        LSTM_STEP(0, 1, 2, 512)
        LSTM_STEP(1, 0, 3, 512)
    }
    // tail: up to 3 steps (dynamic cur/inc; may cross a chunk boundary)
    for (; t < len; t++) {
        if ((t & 127) == 0) {
            if (tid < 128) xs[tid] = xg[t + tid];
            __syncthreads();
        }
        const int cur = t & 1;
        const float2 xv = xs[t & 127];
        f16x8 Af[4];
#pragma unroll
        for (int kt = 0; kt < 4; kt++)
            Af[kt] = *(const f16x8*)(&h_sh[cur][32 * kt + 8 * q]);
        f32x4 acc[8], acc2[8];
#pragma unroll
        for (int s = 0; s < 8; s++) {
            acc[s]  = __builtin_amdgcn_mfma_f32_16x16x32_f16(Af[0], Bf[s][0], z4, 0, 0, 0);
            acc2[s] = __builtin_amdgcn_mfma_f32_16x16x32_f16(Af[2], Bf[s][2], z4, 0, 0, 0);
        }
#pragma unroll
        for (int s = 0; s < 8; s++) {
            acc[s]  = __builtin_amdgcn_mfma_f32_16x16x32_f16(Af[1], Bf[s][1], acc[s],  0, 0, 0);
            acc2[s] = __builtin_amdgcn_mfma_f32_16x16x32_f16(Af[3], Bf[s][3], acc2[s], 0, 0, 0);
        }
        float G0 = (sel ? acc[1][0] + acc2[1][0] : acc[0][0] + acc2[0][0])
                   + __builtin_fmaf(wy0, xv.y, wx0 * xv.x);
        float G1 = (sel ? acc[3][0] + acc2[3][0] : acc[2][0] + acc2[2][0])
                   + __builtin_fmaf(wy1, xv.y, wx1 * xv.x);
        float G2 = (sel ? acc[5][0] + acc2[5][0] : acc[4][0] + acc2[4][0])
                   + __builtin_fmaf(wy2, xv.y, wx2 * xv.x);
        float G3 = (sel ? acc[7][0] + acc2[7][0] : acc[6][0] + acc2[6][0])
                   + __builtin_fmaf(wy3, xv.y, wx3 * xv.x);
        const float ig = sigmoid_f(G0);
        const float fg = sigmoid_f(G1);
        const float gg = tanh_f(G2);
        const float og = sigmoid_f(G3);
        c_reg = __builtin_fmaf(fg, c_reg, ig * gg);
        h_reg = og * tanh_f(fminf(fmaxf(c_reg, -15.f), 15.f));
        if (writer) {
            const f16 h16 = (f16)h_reg;
            *(f16*)hp = h16;
            h_sh[cur ^ 1][j] = h16;
        }
        hp += 512 + (((t & 3) == 0) ? 16 : 0);
        asm volatile("s_waitcnt lgkmcnt(0)" ::: "memory");
        __builtin_amdgcn_sched_barrier(0);
        __builtin_amdgcn_s_barrier();
        __builtin_amdgcn_sched_barrier(0);
    }
#undef LSTM_STEP

    if (writer) {
        out[HT_BASE + (size_t)b * H_ + j] = h_reg;
        out[CT_BASE + (size_t)b * H_ + j] = c_reg;
    }
}

// ---------------------------------------------------------------------------
// Projection GEMM: C[bt, n] = hs[bt,:] . Wn[n,:] + bias, masked by t<len.
__global__ __launch_bounds__(256) void proj_k(const int* __restrict__ lengths,
                                              const f16* __restrict__ Wn,
                                              const float* __restrict__ note_b,
                                              const float* __restrict__ dur_b,
                                              float* __restrict__ out) {
    __shared__ __align__(16) f16 wn_sh[144 * 136];

    const int tid = threadIdx.x;
    {
        unsigned int* dst = (unsigned int*)wn_sh;
        const unsigned int* src = (const unsigned int*)Wn;
        for (int w = tid; w < 144 * 64; w += 256) {
            int row = w >> 6, cw = w & 63;
            dst[row * 68 + cw] = src[w];
        }
    }
    __syncthreads();

    const int wv = tid >> 6;
    const int l = tid & 63;
    const int tile = blockIdx.x * 4 + wv;
    const int bt0 = tile * 16;
    const int b = bt0 >> 11;
    const int t0 = bt0 & 2047;
    const int len = lengths[b];
    const int r16 = l & 15, q = l >> 4;

    f32x4 acc[9];
#pragma unroll
    for (int nf = 0; nf < 9; nf++) acc[nf] = f32x4{0.f, 0.f, 0.f, 0.f};

    const bool live = (t0 < len);
    if (live) {
        f16x8 a[4];
        {
            const f16* ar = hs_row(out, bt0 + r16);
#pragma unroll
            for (int kk = 0; kk < 4; kk++)
                a[kk] = *(const f16x8*)(ar + kk * 32 + q * 8);
        }
#pragma unroll
        for (int nf = 0; nf < 9; nf++) {
            const f16* brow = wn_sh + (nf * 16 + r16) * 136 + q * 8;
#pragma unroll
            for (int kk = 0; kk < 4; kk++) {
                f16x8 bb = *(const f16x8*)(brow + kk * 32);
                acc[nf] = __builtin_amdgcn_mfma_f32_16x16x32_f16(a[kk], bb, acc[nf], 0, 0, 0);
            }
        }
    }

#pragma unroll
    for (int nf = 0; nf < 9; nf++) {
        int col = nf * 16 + r16;
        float bias = 0.f;
        if (col < 129)       bias = note_b[col];
        else if (col == 129) bias = dur_b[0];
#pragma unroll
        for (int r = 0; r < 4; r++) {
            int rowbt = bt0 + q * 4 + r;
            int t = t0 + q * 4 + r;
            float v = (t < len) ? (acc[nf][r] + bias) : 0.f;
            if (col < 129)
                out[(size_t)rowbt * P_ + col] = v;
            else if (col == 129)
                out[DUR_BASE + rowbt] = v;
        }
    }
}

// ---------------------------------------------------------------------------
extern "C" void kernel_launch(void* const* d_in, const int* in_sizes, int n_in,
                              void* d_out, int out_size, void* d_ws, size_t ws_size,
                              hipStream_t stream) {
    const float* x       = (const float*)d_in[0];
    const int*   lengths = (const int*)d_in[1];
    const float* W_ih    = (const float*)d_in[2];
    const float* W_hh    = (const float*)d_in[3];
    const float* note_W  = (const float*)d_in[4];
    const float* note_b  = (const float*)d_in[5];
    const float* dur_W   = (const float*)d_in[6];
    const float* dur_b   = (const float*)d_in[7];
    float* out = (float*)d_out;
    f16* Wn = (f16*)d_ws;

    prep_k<<<72, 256, 0, stream>>>(note_W, dur_W, Wn);
    lstm12_k<<<B_, 256, 0, stream>>>(x, lengths, W_ih, W_hh, out);
    proj_k<<<(B_ * T_) / 64, 256, 0, stream>>>(lengths, Wn, note_b, dur_b, out);
}

// Round 19
// 970.744 us; speedup vs baseline: 1.8520x; 1.0087x over previous
//
#include <hip/hip_runtime.h>

// ---------------------------------------------------------------------------
// MusicLSTM: B=256, T=2048, I=2, H=128 (4H=512 gates), P=129 pitches.
//   prep_k   : note_W+dur_W -> f16 Wn[144][128] in ws
//   lstm13_k : r18's structure (1 WG = 256 thr = 4 waves = 1/SIMD per batch;
//              gates[512] = W_hh . h via MFMA 16x16x32, h broadcast as A;
//              wave w owns n-tiles {w+4s}; static acc indices + cndmask;
//              2x2-deep MFMA chains; pre-selected W_ih coeffs; 4-step unroll
//              with static cur/hp-inc; raw per-step s_barrier with lgkm-only
//              drain, hs stores in flight) plus TRANS-FUSION in the cell
//              update: the 3 divisions feeding c merge into one rcp
//              (c_new = (c*A*C + B*D)/(A*B*C), A=1+e_i B=1+e_f C=e_g+1
//              D=e_g-1) and o*tanh(c) merges into one rcp
//              (h = (e_c-1)/((1+e_o)(e_c+1))): 10 -> 7 quarter-rate trans
//              ops/step (-48 issue cyc + shorter serial chain). Exact
//              algebra, no approximation; products bounded by 2^71 (|G|<13).
//   proj_k   : MFMA f16 GEMM over hs -> note/dur logits, masked rows zeroed.
// Fragment layout conventions (verified by the passing proj_k / r10):
//   A: lane l holds A[m=l&15][k=32*kt+8*(l>>4)+e], e=0..7
//   B: lane l holds B[n=l&15][k=32*kt+8*(l>>4)+e]
//   D: lane l reg r holds D[m=(l>>4)*4+r][n=l&15]
// ---------------------------------------------------------------------------

typedef _Float16 f16;
typedef _Float16 f16x8 __attribute__((ext_vector_type(8)));
typedef float    f32x4 __attribute__((ext_vector_type(4)));

#define B_  256
#define T_  2048
#define H_  128
#define P_  129

static constexpr size_t NOTE_N   = (size_t)B_ * T_ * P_;
static constexpr size_t DUR_BASE = NOTE_N;
static constexpr size_t HT_BASE  = DUR_BASE + (size_t)B_ * T_;
static constexpr size_t CT_BASE  = HT_BASE + (size_t)B_ * H_;

#if defined(__has_builtin)
#if __has_builtin(__builtin_amdgcn_exp2f)
#define EXP2F(x) __builtin_amdgcn_exp2f(x)
#endif
#endif
#ifndef EXP2F
#define EXP2F(x) __expf((x) * 0.6931471805599453f)
#endif

__device__ __forceinline__ float fast_rcp(float x) { return __builtin_amdgcn_rcpf(x); }

// hs row bt lives at the front of note row bt, rounded up to 16B alignment.
__device__ __forceinline__ f16* hs_row(float* out, int bt) {
    size_t byteoff = ((size_t)bt * (P_ * 4) + 15) & ~(size_t)15;
    return (f16*)((char*)out + byteoff);
}

// ---------------------------------------------------------------------------
__global__ __launch_bounds__(256) void prep_k(const float* __restrict__ note_W,
                                              const float* __restrict__ dur_W,
                                              f16* __restrict__ Wn) {
    int i = threadIdx.x + blockIdx.x * 256;
    if (i >= 144 * 128) return;
    int row = i >> 7, k = i & 127;
    float v = 0.f;
    if (row < 129)       v = note_W[row * 128 + k];
    else if (row == 129) v = dur_W[k];
    Wn[i] = (f16)v;
}

// ---------------------------------------------------------------------------
__global__ __launch_bounds__(256, 1) void lstm13_k(const float* __restrict__ x,
                                                   const int* __restrict__ lengths,
                                                   const float* __restrict__ W_ih,
                                                   const float* __restrict__ W_hh,
                                                   float* __restrict__ out) {
    __shared__ __align__(16) f16 h_sh[2][H_];   // double-buffered h (512 B)
    __shared__ __align__(8) float2 xs[128];     // x chunk: 128 steps (1 KB)

    const int tid = threadIdx.x;
    const int b = blockIdx.x;
    const int w = tid >> 6;       // wave 0..3 (one per SIMD)
    const int l = tid & 63;
    const int p = l & 15;
    const int q = l >> 4;
    const int sel = q >> 1;                    // 0: col j=16w+p, 1: j=16w+64+p
    const int j = 16 * w + 64 * sel + p;       // this lane's hidden column
    const bool writer = ((q & 1) == 0);

    // B-fragments: 8 gate-row groups nt = w+4s; global row c = 16*nt + p.
    f16x8 Bf[8][4];
    float wxx[8], wxy[8];
#pragma unroll
    for (int s = 0; s < 8; s++) {
        const int c = 16 * (w + 4 * s) + p;
        const float* wr = W_hh + (size_t)c * H_ + 8 * q;
#pragma unroll
        for (int kt = 0; kt < 4; kt++) {
            float4 v1 = *(const float4*)(wr + 32 * kt);
            float4 v2 = *(const float4*)(wr + 32 * kt + 4);
            f16x8 f;
            f[0] = (f16)v1.x; f[1] = (f16)v1.y; f[2] = (f16)v1.z; f[3] = (f16)v1.w;
            f[4] = (f16)v2.x; f[5] = (f16)v2.y; f[6] = (f16)v2.z; f[7] = (f16)v2.w;
            Bf[s][kt] = f;
        }
        wxx[s] = W_ih[2 * c];
        wxy[s] = W_ih[2 * c + 1];
    }
    // Pre-select this lane's W_ih coefficients (cndmask once at init):
    const float wx0 = sel ? wxx[1] : wxx[0], wy0 = sel ? wxy[1] : wxy[0];
    const float wx1 = sel ? wxx[3] : wxx[2], wy1 = sel ? wxy[3] : wxy[2];
    const float wx2 = sel ? wxx[5] : wxx[4], wy2 = sel ? wxy[5] : wxy[4];
    const float wx3 = sel ? wxx[7] : wxx[6], wy3 = sel ? wxy[7] : wxy[6];

    const int len = lengths[b];
    if (tid < 2 * H_) ((f16*)h_sh)[tid] = (f16)0.f;

    // incremental hs store pointer (row stride pattern 528,512,512,512)
    char* hp = (char*)out + (size_t)b * (T_ * 516ULL) + 2 * j;

    const f32x4 z4 = {0.f, 0.f, 0.f, 0.f};
    float c_reg = 0.f, h_reg = 0.f;
    const float2* xg = (const float2*)(x + (size_t)b * T_ * 2);

// Fused cell update: 7 trans ops (4+1 exp, 2 rcp) instead of 10.
//   c_new = (c*A*C + B*D)/(A*B*C); h = (e_c-1)/((1+e_o)(e_c+1))
#define CELL_UPDATE()                                                          \
    {                                                                          \
        const float e0 = EXP2F(-1.44269504f * G0);   /* i */                   \
        const float e1 = EXP2F(-1.44269504f * G1);   /* f */                   \
        const float e2 = EXP2F(2.885390082f * G2);   /* tanh g */              \
        const float e3 = EXP2F(-1.44269504f * G3);   /* o */                   \
        const float Aa = 1.f + e0, Bb = 1.f + e1;                              \
        const float Cc = e2 + 1.f, Dd = e2 - 1.f;                              \
        const float t1 = Aa * Cc;                                              \
        const float num = __builtin_fmaf(c_reg, t1, Bb * Dd);                  \
        c_reg = num * fast_rcp(Bb * t1);                                       \
        const float cc = fminf(fmaxf(c_reg, -15.f), 15.f);                     \
        const float ec = EXP2F(2.885390082f * cc);                             \
        h_reg = (ec - 1.f) * fast_rcp((1.f + e3) * (ec + 1.f));                \
    }

// One LSTM step with compile-time CUR/NXT buffer ids, x offset, hp increment.
#define LSTM_STEP(CUR, NXT, XOFF, INC)                                         \
    {                                                                          \
        const float2 xv = xc[XOFF];                                            \
        f16x8 Af[4];                                                           \
        _Pragma("unroll")                                                      \
        for (int kt = 0; kt < 4; kt++)                                         \
            Af[kt] = *(const f16x8*)(&h_sh[CUR][32 * kt + 8 * q]);             \
        f32x4 acc[8], acc2[8];                                                 \
        _Pragma("unroll")                                                      \
        for (int s = 0; s < 8; s++) {                                          \
            acc[s]  = __builtin_amdgcn_mfma_f32_16x16x32_f16(Af[0], Bf[s][0], z4, 0, 0, 0);      \
            acc2[s] = __builtin_amdgcn_mfma_f32_16x16x32_f16(Af[2], Bf[s][2], z4, 0, 0, 0);      \
        }                                                                      \
        _Pragma("unroll")                                                      \
        for (int s = 0; s < 8; s++) {                                          \
            acc[s]  = __builtin_amdgcn_mfma_f32_16x16x32_f16(Af[1], Bf[s][1], acc[s],  0, 0, 0); \
            acc2[s] = __builtin_amdgcn_mfma_f32_16x16x32_f16(Af[3], Bf[s][3], acc2[s], 0, 0, 0); \
        }                                                                      \
        float G0 = (sel ? acc[1][0] + acc2[1][0] : acc[0][0] + acc2[0][0])     \
                   + __builtin_fmaf(wy0, xv.y, wx0 * xv.x);                    \
        float G1 = (sel ? acc[3][0] + acc2[3][0] : acc[2][0] + acc2[2][0])     \
                   + __builtin_fmaf(wy1, xv.y, wx1 * xv.x);                    \
        float G2 = (sel ? acc[5][0] + acc2[5][0] : acc[4][0] + acc2[4][0])     \
                   + __builtin_fmaf(wy2, xv.y, wx2 * xv.x);                    \
        float G3 = (sel ? acc[7][0] + acc2[7][0] : acc[6][0] + acc2[6][0])     \
                   + __builtin_fmaf(wy3, xv.y, wx3 * xv.x);                    \
        CELL_UPDATE()                                                          \
        if (writer) {                                                          \
            const f16 h16 = (f16)h_reg;                                        \
            *(f16*)hp = h16;            /* global, stays in flight */          \
            h_sh[NXT][j] = h16;         /* LDS (lgkm) */                       \
        }                                                                      \
        hp += (INC);                                                           \
        asm volatile("s_waitcnt lgkmcnt(0)" ::: "memory");                     \
        __builtin_amdgcn_sched_barrier(0);                                     \
        __builtin_amdgcn_s_barrier();                                          \
        __builtin_amdgcn_sched_barrier(0);                                     \
    }

    int t = 0;
    for (; t + 4 <= len; t += 4) {
        if ((t & 127) == 0) {
            // refill x chunk [t, t+128). Prev step's lgkm+barrier already
            // drained old-chunk reads; one syncthreads publishes the writes
            // (and, at t=0, the h_sh zeroing).
            if (tid < 128) xs[tid] = xg[t + tid];
            __syncthreads();
        }
        const float2* xc = &xs[t & 127];
        LSTM_STEP(0, 1, 0, 528)
        LSTM_STEP(1, 0, 1, 512)
        LSTM_STEP(0, 1, 2, 512)
        LSTM_STEP(1, 0, 3, 512)
    }
    // tail: up to 3 steps (dynamic cur/inc; may cross a chunk boundary)
    for (; t < len; t++) {
        if ((t & 127) == 0) {
            if (tid < 128) xs[tid] = xg[t + tid];
            __syncthreads();
        }
        const int cur = t & 1;
        const float2 xv = xs[t & 127];
        f16x8 Af[4];
#pragma unroll
        for (int kt = 0; kt < 4; kt++)
            Af[kt] = *(const f16x8*)(&h_sh[cur][32 * kt + 8 * q]);
        f32x4 acc[8], acc2[8];
#pragma unroll
        for (int s = 0; s < 8; s++) {
            acc[s]  = __builtin_amdgcn_mfma_f32_16x16x32_f16(Af[0], Bf[s][0], z4, 0, 0, 0);
            acc2[s] = __builtin_amdgcn_mfma_f32_16x16x32_f16(Af[2], Bf[s][2], z4, 0, 0, 0);
        }
#pragma unroll
        for (int s = 0; s < 8; s++) {
            acc[s]  = __builtin_amdgcn_mfma_f32_16x16x32_f16(Af[1], Bf[s][1], acc[s],  0, 0, 0);
            acc2[s] = __builtin_amdgcn_mfma_f32_16x16x32_f16(Af[3], Bf[s][3], acc2[s], 0, 0, 0);
        }
        float G0 = (sel ? acc[1][0] + acc2[1][0] : acc[0][0] + acc2[0][0])
                   + __builtin_fmaf(wy0, xv.y, wx0 * xv.x);
        float G1 = (sel ? acc[3][0] + acc2[3][0] : acc[2][0] + acc2[2][0])
                   + __builtin_fmaf(wy1, xv.y, wx1 * xv.x);
        float G2 = (sel ? acc[5][0] + acc2[5][0] : acc[4][0] + acc2[4][0])
                   + __builtin_fmaf(wy2, xv.y, wx2 * xv.x);
        float G3 = (sel ? acc[7][0] + acc2[7][0] : acc[6][0] + acc2[6][0])
                   + __builtin_fmaf(wy3, xv.y, wx3 * xv.x);
        CELL_UPDATE()
        if (writer) {
            const f16 h16 = (f16)h_reg;
            *(f16*)hp = h16;
            h_sh[cur ^ 1][j] = h16;
        }
        hp += 512 + (((t & 3) == 0) ? 16 : 0);
        asm volatile("s_waitcnt lgkmcnt(0)" ::: "memory");
        __builtin_amdgcn_sched_barrier(0);
        __builtin_amdgcn_s_barrier();
        __builtin_amdgcn_sched_barrier(0);
    }
#undef LSTM_STEP
#undef CELL_UPDATE

    if (writer) {
        out[HT_BASE + (size_t)b * H_ + j] = h_reg;
        out[CT_BASE + (size_t)b * H_ + j] = c_reg;
    }
}

// ---------------------------------------------------------------------------
// Projection GEMM: C[bt, n] = hs[bt,:] . Wn[n,:] + bias, masked by t<len.
__global__ __launch_bounds__(256) void proj_k(const int* __restrict__ lengths,
                                              const f16* __restrict__ Wn,
                                              const float* __restrict__ note_b,
                                              const float* __restrict__ dur_b,
                                              float* __restrict__ out) {
    __shared__ __align__(16) f16 wn_sh[144 * 136];

    const int tid = threadIdx.x;
    {
        unsigned int* dst = (unsigned int*)wn_sh;
        const unsigned int* src = (const unsigned int*)Wn;
        for (int w = tid; w < 144 * 64; w += 256) {
            int row = w >> 6, cw = w & 63;
            dst[row * 68 + cw] = src[w];
        }
    }
    __syncthreads();

    const int wv = tid >> 6;
    const int l = tid & 63;
    const int tile = blockIdx.x * 4 + wv;
    const int bt0 = tile * 16;
    const int b = bt0 >> 11;
    const int t0 = bt0 & 2047;
    const int len = lengths[b];
    const int r16 = l & 15, q = l >> 4;

    f32x4 acc[9];
#pragma unroll
    for (int nf = 0; nf < 9; nf++) acc[nf] = f32x4{0.f, 0.f, 0.f, 0.f};

    const bool live = (t0 < len);
    if (live) {
        f16x8 a[4];
        {
            const f16* ar = hs_row(out, bt0 + r16);
#pragma unroll
            for (int kk = 0; kk < 4; kk++)
                a[kk] = *(const f16x8*)(ar + kk * 32 + q * 8);
        }
#pragma unroll
        for (int nf = 0; nf < 9; nf++) {
            const f16* brow = wn_sh + (nf * 16 + r16) * 136 + q * 8;
#pragma unroll
            for (int kk = 0; kk < 4; kk++) {
                f16x8 bb = *(const f16x8*)(brow + kk * 32);
                acc[nf] = __builtin_amdgcn_mfma_f32_16x16x32_f16(a[kk], bb, acc[nf], 0, 0, 0);
            }
        }
    }

#pragma unroll
    for (int nf = 0; nf < 9; nf++) {
        int col = nf * 16 + r16;
        float bias = 0.f;
        if (col < 129)       bias = note_b[col];
        else if (col == 129) bias = dur_b[0];
#pragma unroll
        for (int r = 0; r < 4; r++) {
            int rowbt = bt0 + q * 4 + r;
            int t = t0 + q * 4 + r;
            float v = (t < len) ? (acc[nf][r] + bias) : 0.f;
            if (col < 129)
                out[(size_t)rowbt * P_ + col] = v;
            else if (col == 129)
                out[DUR_BASE + rowbt] = v;
        }
    }
}

// ---------------------------------------------------------------------------
extern "C" void kernel_launch(void* const* d_in, const int* in_sizes, int n_in,
                              void* d_out, int out_size, void* d_ws, size_t ws_size,
                              hipStream_t stream) {
    const float* x       = (const float*)d_in[0];
    const int*   lengths = (const int*)d_in[1];
    const float* W_ih    = (const float*)d_in[2];
    const float* W_hh    = (const float*)d_in[3];
    const float* note_W  = (const float*)d_in[4];
    const float* note_b  = (const float*)d_in[5];
    const float* dur_W   = (const float*)d_in[6];
    const float* dur_b   = (const float*)d_in[7];
    float* out = (float*)d_out;
    f16* Wn = (f16*)d_ws;

    prep_k<<<72, 256, 0, stream>>>(note_W, dur_W, Wn);
    lstm13_k<<<B_, 256, 0, stream>>>(x, lengths, W_ih, W_hh, out);
    proj_k<<<(B_ * T_) / 64, 256, 0, stream>>>(lengths, Wn, note_b, dur_b, out);
}